// Round 1
// baseline (123.130 us; speedup 1.0000x reference)
//
#include <hip/hip_runtime.h>
#include <hip/hip_bf16.h>

// out = softmax((X Wq + bq)(X Wk + bk)^T / 8) (X Wv + bv) Wo + bo
// All prune/straight-through ops in the reference are value-wise identity.
//
// Pipeline (all bf16 MFMA 16x16x32, fp32 accum):
//   k_cvt : hs fp32 -> bf16 A [4616][768]
//   k_wt  : W fp32 [k][n] -> bf16 Wt [n][k]  (x4 weights)
//   k_gemm: QKV projections (z=0,1,2) -> qh/kh [B,h,S,64] bf16, vt [B,h,64,S+pad]
//   k_attn: flash attention per (b,h,qtile64) -> ctx [B,S,768] bf16
//   k_gemm mode 3: ctx @ Wo + bo -> d_out fp32

#define B_ 8
#define S_ 577
#define H_ 768
#define NH_ 12
#define HD_ 64
#define M_ (B_*S_)     /* 4616 */
#define BH_ (B_*NH_)   /* 96 */
#define VSTR 584       /* padded S stride for Vt rows (16B aligned) */

typedef __attribute__((ext_vector_type(8))) short short8;
typedef __attribute__((ext_vector_type(4))) float f32x4;

__device__ inline unsigned short f2bf(float f){
    unsigned int u = __float_as_uint(f);
    u = u + 0x7fffu + ((u>>16)&1u);     // round-to-nearest-even
    return (unsigned short)(u>>16);
}

__global__ __launch_bounds__(256) void k_cvt(const float* __restrict__ x, short* __restrict__ y){
    int i = blockIdx.x*256 + threadIdx.x;
    const float4* p = (const float4*)(x + (size_t)i*8);
    float4 a = p[0], b = p[1];
    short8 v;
    v[0]=(short)f2bf(a.x); v[1]=(short)f2bf(a.y); v[2]=(short)f2bf(a.z); v[3]=(short)f2bf(a.w);
    v[4]=(short)f2bf(b.x); v[5]=(short)f2bf(b.y); v[6]=(short)f2bf(b.z); v[7]=(short)f2bf(b.w);
    *(short8*)(y + (size_t)i*8) = v;
}

// transpose + convert: T[n][k] = bf16(W[k][n])
__global__ __launch_bounds__(256) void k_wt(const float* __restrict__ Wq, const float* __restrict__ Wk,
                                            const float* __restrict__ Wv, const float* __restrict__ Wo,
                                            short* __restrict__ Tq, short* __restrict__ Tk,
                                            short* __restrict__ Tv, short* __restrict__ To){
    const float* W = blockIdx.z==0?Wq: blockIdx.z==1?Wk: blockIdx.z==2?Wv:Wo;
    short*       T = blockIdx.z==0?Tq: blockIdx.z==1?Tk: blockIdx.z==2?Tv:To;
    __shared__ float lds[64][65];
    int t = threadIdx.x;
    int k0 = blockIdx.x*64, n0 = blockIdx.y*64;
    for(int i=0;i<4;i++){
        int row = i*16 + (t>>4);
        int col = (t&15)*4;
        float4 v = *(const float4*)&W[(k0+row)*768 + n0 + col];
        lds[row][col]=v.x; lds[row][col+1]=v.y; lds[row][col+2]=v.z; lds[row][col+3]=v.w;
    }
    __syncthreads();
    for(int i=0;i<4;i++){
        int n = i*16 + (t>>4);
        int k4 = (t&15)*4;
        for(int j=0;j<4;j++)
            T[(n0+n)*768 + k0 + k4 + j] = (short)f2bf(lds[k4+j][n]);
    }
}

// 64x64 tile GEMM: out[m][n] = sum_k A[m][k]*T[n][k] + bias[n]
// mode 0 (grid z=0,1,2): write q/k head-major bf16, v transposed bf16
// mode 3: write fp32 to of[m*768+n]
__global__ __launch_bounds__(256) void k_gemm(
    const short* __restrict__ A,
    const short* __restrict__ T0, const short* __restrict__ T1, const short* __restrict__ T2,
    const float* __restrict__ b0, const float* __restrict__ b1, const float* __restrict__ b2,
    short* __restrict__ oq, short* __restrict__ ok, short* __restrict__ ovt,
    float* __restrict__ of, int mode)
{
    __shared__ short lA[64*64], lB[64*64];
    const int t = threadIdx.x;
    const int m0 = blockIdx.x*64, n0 = blockIdx.y*64;
    const int z = blockIdx.z;
    const short* T    = (mode==3)? T0 : (z==0?T0: z==1?T1:T2);
    const float* bias = (mode==3)? b0 : (z==0?b0: z==1?b1:b2);

    const int w = t>>6, lane = t&63, g = lane>>4, c = lane&15;
    const int wm = w>>1, wn = w&1;

    f32x4 acc[2][2] = {};

    for(int kk=0; kk<12; kk++){
        for(int ch=0; ch<2; ch++){
            int idx = t + ch*256;
            int row = idx>>3, e8 = (idx&7)*8;
            int sw = row*64 + (e8 ^ ((row&7)<<3));
            int m = m0 + row;
            short8 va = {};
            if(m < M_) va = *(const short8*)&A[m*768 + kk*64 + e8];
            *(short8*)&lA[sw] = va;
            *(short8*)&lB[sw] = *(const short8*)&T[(n0+row)*768 + kk*64 + e8];
        }
        __syncthreads();
        short8 af[2][2], bf[2][2];
        for(int mi=0; mi<2; mi++) for(int ks=0; ks<2; ks++){
            int row = wm*32 + mi*16 + c;
            af[mi][ks] = *(const short8*)&lA[row*64 + ((ks*32 + g*8) ^ ((row&7)<<3))];
        }
        for(int ni=0; ni<2; ni++) for(int ks=0; ks<2; ks++){
            int row = wn*32 + ni*16 + c;
            bf[ni][ks] = *(const short8*)&lB[row*64 + ((ks*32 + g*8) ^ ((row&7)<<3))];
        }
        for(int mi=0; mi<2; mi++) for(int ni=0; ni<2; ni++)
            for(int ks=0; ks<2; ks++)
                acc[mi][ni] = __builtin_amdgcn_mfma_f32_16x16x32_bf16(af[mi][ks], bf[ni][ks], acc[mi][ni], 0,0,0);
        __syncthreads();
    }

    for(int mi=0; mi<2; mi++) for(int ni=0; ni<2; ni++){
        for(int r=0; r<4; r++){
            int m = m0 + wm*32 + mi*16 + g*4 + r;   // C/D: row=(lane>>4)*4+reg
            int n = n0 + wn*32 + ni*16 + c;         // C/D: col=lane&15
            if(m >= M_) continue;
            float val = acc[mi][ni][r] + bias[n];
            if(mode==3){
                of[(size_t)m*768 + n] = val;
            } else {
                int s = m % S_, b = m / S_;
                int h = n >> 6, d = n & 63;
                if(z==2)      ovt[(((size_t)b*NH_+h)*HD_ + d)*VSTR + s] = (short)f2bf(val);
                else if(z==1) ok [(((size_t)b*NH_+h)*S_ + s)*HD_ + d] = (short)f2bf(val);
                else          oq [(((size_t)b*NH_+h)*S_ + s)*HD_ + d] = (short)f2bf(val);
            }
        }
    }
}

// flash attention: block = (qtile of 64 rows) x (b,h); 4 waves, 16 q-rows each
__global__ __launch_bounds__(256) void k_attn(
    const short* __restrict__ qh, const short* __restrict__ kh, const short* __restrict__ vt,
    short* __restrict__ ctx)
{
    __shared__ short lK[64*64], lV[64*64], lP[4*16*64];
    const int t = threadIdx.x;
    const int w = t>>6, lane = t&63, g = lane>>4, c = lane&15;
    const int bh = blockIdx.y, b = bh/NH_, h = bh%NH_;
    const int q0 = blockIdx.x*64;

    // stage Q tile through lK, pull per-wave Q fragments to registers
    for(int ch=0; ch<2; ch++){
        int idx = t + ch*256;
        int row = idx>>3, e8 = (idx&7)*8;
        int s = q0 + row;
        short8 v = {};
        if(s < S_) v = *(const short8*)&qh[((size_t)bh*S_ + s)*HD_ + e8];
        *(short8*)&lK[row*64 + (e8 ^ ((row&7)<<3))] = v;
    }
    __syncthreads();
    short8 qf[2];
    {
        int row = w*16 + c;
        for(int ks=0; ks<2; ks++)
            qf[ks] = *(const short8*)&lK[row*64 + ((ks*32+g*8) ^ ((row&7)<<3))];
    }
    __syncthreads();

    float m_run[4], l_run[4];
    f32x4 O[4] = {};
    for(int r=0;r<4;r++){ m_run[r] = -3e38f; l_run[r] = 0.f; }

    for(int kt=0; kt<10; kt++){
        int key0 = kt*64;
        for(int ch=0; ch<2; ch++){
            int idx = t + ch*256;
            int row = idx>>3, e8 = (idx&7)*8;
            int sw = row*64 + (e8 ^ ((row&7)<<3));
            int key = key0 + row;
            short8 vk = {};
            if(key < S_) vk = *(const short8*)&kh[((size_t)bh*S_ + key)*HD_ + e8];
            *(short8*)&lK[sw] = vk;
            short8 vv = {};
            const short* src = &vt[((size_t)bh*HD_ + row)*VSTR + key0 + e8];
            if(key0 + e8 + 7 < S_) vv = *(const short8*)src;
            else { for(int j=0;j<8;j++) vv[j] = (key0+e8+j < S_) ? src[j] : (short)0; }
            *(short8*)&lV[sw] = vv;
        }
        __syncthreads();

        // S = Q K^T (per wave: 16 q-rows x 64 keys)
        float sv[4][4];
        for(int nt=0; nt<4; nt++){
            f32x4 sa = {};
            int row = nt*16 + c;
            for(int ks=0; ks<2; ks++){
                short8 kf = *(const short8*)&lK[row*64 + ((ks*32+g*8) ^ ((row&7)<<3))];
                sa = __builtin_amdgcn_mfma_f32_16x16x32_bf16(qf[ks], kf, sa, 0,0,0);
            }
            int key = key0 + nt*16 + c;
            for(int r=0;r<4;r++)
                sv[nt][r] = (key < S_) ? sa[r]*0.125f : -3e38f;
        }
        // online softmax (rows live on 16-lane groups; butterfly over lane&15)
        float fac[4], ts[4];
        for(int r=0;r<4;r++){
            float mx = fmaxf(fmaxf(sv[0][r],sv[1][r]),fmaxf(sv[2][r],sv[3][r]));
            for(int off=1; off<16; off<<=1) mx = fmaxf(mx, __shfl_xor(mx, off));
            float nm = fmaxf(m_run[r], mx);
            fac[r] = __expf(m_run[r] - nm);
            m_run[r] = nm;
            ts[r] = 0.f;
        }
        for(int nt=0; nt<4; nt++){
            for(int r=0;r<4;r++){
                float p = __expf(sv[nt][r] - m_run[r]);
                ts[r] += p;
                int prow = g*4 + r;
                lP[w*1024 + prow*64 + ((nt*16 + c) ^ ((prow&7)<<3))] = (short)f2bf(p);
            }
        }
        for(int r=0;r<4;r++){
            for(int off=1; off<16; off<<=1) ts[r] += __shfl_xor(ts[r], off);
            l_run[r] = l_run[r]*fac[r] + ts[r];
        }
        for(int nt=0;nt<4;nt++) for(int r=0;r<4;r++) O[nt][r] *= fac[r];

        // O += P V   (P from per-wave LDS, V^T tile in lV)
        short8 pf[2];
        for(int ks=0; ks<2; ks++)
            pf[ks] = *(const short8*)&lP[w*1024 + c*64 + ((ks*32+g*8) ^ ((c&7)<<3))];
        for(int nt=0; nt<4; nt++){
            int vrow = nt*16 + c;
            for(int ks=0; ks<2; ks++){
                short8 vf = *(const short8*)&lV[vrow*64 + ((ks*32+g*8) ^ ((vrow&7)<<3))];
                O[nt] = __builtin_amdgcn_mfma_f32_16x16x32_bf16(pf[ks], vf, O[nt], 0,0,0);
            }
        }
        __syncthreads();
    }

    for(int nt=0; nt<4; nt++){
        for(int r=0;r<4;r++){
            int s = q0 + w*16 + g*4 + r;
            if(s < S_){
                float val = O[nt][r] / l_run[r];
                ctx[((size_t)b*S_ + s)*H_ + h*HD_ + nt*16 + c] = (short)f2bf(val);
            }
        }
    }
}

extern "C" void kernel_launch(void* const* d_in, const int* in_sizes, int n_in,
                              void* d_out, int out_size, void* d_ws, size_t ws_size,
                              hipStream_t stream)
{
    const float* hs = (const float*)d_in[0];
    const float* Wq = (const float*)d_in[1];
    const float* bq = (const float*)d_in[2];
    const float* Wk = (const float*)d_in[3];
    const float* bk = (const float*)d_in[4];
    const float* Wv = (const float*)d_in[5];
    const float* bv = (const float*)d_in[6];
    const float* Wo = (const float*)d_in[7];
    const float* bo = (const float*)d_in[8];
    float* out = (float*)d_out;

    char* ws = (char*)d_ws;
    // abf: 4616*768*2 = 7,090,176 B ; Wt x4: 768*768*2 = 1,179,648 B each
    // qh/kh: 96*577*64*2 = 7,090,176 B ; vt: 96*64*584*2 = 7,176,192 B
    short* abf = (short*)(ws);
    short* ctx = abf;                               // reuse after QKV GEMM
    short* wqt = (short*)(ws + 7090176);
    short* wkt = (short*)(ws + 7090176 + 1179648);
    short* wvt = (short*)(ws + 7090176 + 2*1179648);
    short* wot = (short*)(ws + 7090176 + 3*1179648);
    short* qh  = (short*)(ws + 11808768);
    short* kh  = (short*)(ws + 18898944);
    short* vt  = (short*)(ws + 25989120);
    // total: 33,165,312 B

    k_cvt<<<1731, 256, 0, stream>>>(hs, abf);
    k_wt<<<dim3(12,12,4), 256, 0, stream>>>(Wq,Wk,Wv,Wo, wqt,wkt,wvt,wot);
    k_gemm<<<dim3(73,12,3), 256, 0, stream>>>(abf, wqt,wkt,wvt, bq,bk,bv, qh,kh,vt, nullptr, 0);
    k_attn<<<dim3(10,96), 256, 0, stream>>>(qh, kh, vt, ctx);
    k_gemm<<<dim3(73,12,1), 256, 0, stream>>>(ctx, wot,nullptr,nullptr, bo,nullptr,nullptr,
                                              nullptr,nullptr,nullptr, out, 3);
}